// Round 9
// baseline (276.502 us; speedup 1.0000x reference)
//
#include <hip/hip_runtime.h>

// SAModule (PointNet++ SA), R9 = R8 with launch_bounds removed from knn/mlp.
// Evidence model: with MFMA, compiler splits unified RF ~50/50 arch/AGPR under a
// bounds cap -> (128,3) gave 84 arch VGPRs and ~200B/thread scratch spill
// (WRITE_SIZE 104MB). Default cap (256) fits mlp's ~120 arch + 64 AGPR clean
// (proven by R7's (256,2): 120 VGPR, no spill). knn's (256,4)=128 cap was also
// borderline for its ~100-reg scan -> drop it too.
//   prep_kernel : weights -> bf16 B-fragment image in ws
//   knn_kernel  : ball-query KNN (two-pass histogram select) -> nbr/nsel in ws
//   mlp_kernel  : gather feat=[x|rel] -> MLP 67->128->128->256 (bf16 MFMA) -> max

typedef unsigned short u16;
typedef unsigned int u32;
typedef unsigned long long u64;
typedef __bf16 bf16x8 __attribute__((ext_vector_type(8)));
typedef float floatx4 __attribute__((ext_vector_type(4)));

#define PCLOUD 4096
#define DIN    64
#define MCENT  8192
#define KNBR   32

#define WS_W_U4   7680                    // weight image, uint4 count (120 KB)
#define WS_NBR_B  (WS_W_U4 * 16)          // byte offset of nbr[8192][32]
#define WS_NSEL_B (WS_NBR_B + MCENT * KNBR * 4)
#define WS_NEED   (WS_NSEL_B + MCENT * 4)

#define LDS_FENCE() asm volatile("s_waitcnt lgkmcnt(0)" ::: "memory")

__device__ inline u16 f2bf(float f) {          // RNE
    u32 b = __float_as_uint(f);
    b += 0x7fffu + ((b >> 16) & 1u);
    return (u16)(b >> 16);
}
__device__ inline u32 pk2(float a, float b) { return (u32)f2bf(a) | ((u32)f2bf(b) << 16); }
__device__ inline u64 wave_min_u64(u64 v) {
    #pragma unroll
    for (int off = 32; off; off >>= 1) {
        u64 o = __shfl_xor((unsigned long long)v, off);
        if (o < v) v = o;
    }
    return v;
}
__device__ inline u64 d2key(float d2, int j) {
    u32 u = __float_as_uint(d2);
    u = (u & 0x80000000u) ? ~u : (u | 0x80000000u);
    return ((u64)u << 32) | (u32)j;
}
__device__ inline int bktOf(float d2) {
    int b = (int)(d2 * 800.0f);                // 32 buckets over [0, 0.04]
    return b < 0 ? 0 : (b > 31 ? 31 : b);
}

// ---- prep: weights -> bf16 B-fragment image (layout: see loadB) ----
__global__ void prep_kernel(const float* __restrict__ W1, const float* __restrict__ W2,
                            const float* __restrict__ W3, uint4* __restrict__ ws) {
    int t = blockIdx.x * 256 + threadIdx.x;   // 0..7679
    const float* W; int rs, krows, KI, rel;
    if (t < 1536)      { W = W1; rs = 128; krows = 67;  KI = 3; rel = t; }
    else if (t < 3584) { W = W2; rs = 128; krows = 128; KI = 4; rel = t - 1536; }
    else               { W = W3; rs = 256; krows = 128; KI = 4; rel = t - 3584; }
    int m16 = rel & 15, quad = (rel >> 4) & 3, ccki = rel >> 6;
    int ki = ccki % KI, cc = ccki / KI;
    int n = cc * 16 + m16;
    int kb = (ki * 4 + quad) * 8;
    u16 e[8];
    #pragma unroll
    for (int j = 0; j < 8; j++)
        e[j] = (kb + j < krows) ? f2bf(W[(size_t)(kb + j) * rs + n]) : (u16)0;
    ws[t] = *(const uint4*)e;
}

template <bool WS>
__device__ __forceinline__ bf16x8 loadB(const uint4* __restrict__ wsl, int slot,
                                        const float* __restrict__ W, int rs, int krows,
                                        int n, int kb) {
    if constexpr (WS) {
        return __builtin_bit_cast(bf16x8, wsl[slot * 64]);
    } else {
        u16 e[8];
        #pragma unroll
        for (int j = 0; j < 8; j++)
            e[j] = (kb + j < krows) ? f2bf(W[(size_t)(kb + j) * rs + n]) : (u16)0;
        return __builtin_bit_cast(bf16x8, *(const uint4*)e);
    }
}

// ================= KNN kernel: one wave per center (no launch_bounds) =================
__global__ void knn_kernel(
    const float* __restrict__ pos, const int* __restrict__ batch,
    const int* __restrict__ idx, int* __restrict__ nbr, int* __restrict__ nsel,
    float* __restrict__ out) {
    __shared__ u32 hist[4][32];
    __shared__ int cnts[4];
    int tid = threadIdx.x, w = tid >> 6, l = tid & 63;
    int bid = blockIdx.x;
    int m = ((bid & 7) << 10) + ((bid >> 3) << 2) + w;
    int ic = idx[m] & (8 * PCLOUD - 1);
    float cx = pos[ic * 3], cy = pos[ic * 3 + 1], cz = pos[ic * 3 + 2];
    float sc = __fadd_rn(__fadd_rn(__fmul_rn(cx, cx), __fmul_rn(cy, cy)), __fmul_rn(cz, cz));
    int bcl = batch[ic] & 7;
    int base = bcl << 12;
    const float R2 = 0.04f;

    if (l == 1) {
        float* o1 = out + MCENT * 256;
        o1[m * 3] = cx; o1[m * 3 + 1] = cy; o1[m * 3 + 2] = cz;
        (o1 + MCENT * 3)[m] = (float)bcl;
    }
    if (l < 32) hist[w][l] = 0;
    if (l == 0) cnts[w] = 0;
    LDS_FENCE();

    // pass 1: count + histogram
    int c = 0;
    for (int t = l; t < PCLOUD; t += 64) {
        int j = base + t;
        float px = pos[j * 3], py = pos[j * 3 + 1], pz = pos[j * 3 + 2];
        float sp = __fadd_rn(__fadd_rn(__fmul_rn(px, px), __fmul_rn(py, py)), __fmul_rn(pz, pz));
        float dt = __fadd_rn(__fadd_rn(__fmul_rn(cx, px), __fmul_rn(cy, py)), __fmul_rn(cz, pz));
        float d2 = __fsub_rn(__fadd_rn(sc, sp), __fmul_rn(2.0f, dt));
        bool hit = (d2 <= R2);
        c += (int)__popcll(__ballot(hit));
        if (hit) atomicAdd(&hist[w][bktOf(d2)], 1u);
    }
    LDS_FENCE();
    if (l == 0) nsel[m] = c < KNBR ? c : KNBR;

    int B = 32, S = 0;
    if (c > KNBR) {
        int hv = (l < 32) ? (int)hist[w][l] : 0;
        #pragma unroll
        for (int off = 1; off <= 16; off <<= 1) {
            int o = __shfl_up(hv, off);
            if (l >= off) hv += o;
        }
        u64 ge = __ballot((l < 32) && (hv >= KNBR));
        B = __ffsll((unsigned long long)ge) - 1;
        S = (B == 0) ? 0 : __shfl(hv, B - 1);
    }

    // pass 2: bulk-write below-B (order-free; max is order-invariant), capture bucket-B keys
    u64 q0 = ~0ull, q1 = ~0ull, q2 = ~0ull, q3 = ~0ull;
    int nq = 0;
    for (int t = l; t < PCLOUD; t += 64) {
        int j = base + t;
        float px = pos[j * 3], py = pos[j * 3 + 1], pz = pos[j * 3 + 2];
        float sp = __fadd_rn(__fadd_rn(__fmul_rn(px, px), __fmul_rn(py, py)), __fmul_rn(pz, pz));
        float dt = __fadd_rn(__fadd_rn(__fmul_rn(cx, px), __fmul_rn(cy, py)), __fmul_rn(cz, pz));
        float d2 = __fsub_rn(__fadd_rn(sc, sp), __fmul_rn(2.0f, dt));
        if (d2 <= R2) {
            int bkt = bktOf(d2);
            if (bkt < B) {
                int p = atomicAdd(&cnts[w], 1);
                nbr[m * KNBR + p] = j;
            } else if (bkt == B) {
                u64 kk = d2key(d2, j);
                if (nq == 0) q0 = kk; else if (nq == 1) q1 = kk;
                else if (nq == 2) q2 = kk; else if (nq == 3) q3 = kk;
                nq++;
            }
        }
    }
    if (c > KNBR) {
        int need = KNBR - S;
        u64 last = 0;
        if (__ballot(nq > 4) == 0ull) {
            for (int r = 0; r < need; r++) {
                u64 mn = ~0ull;
                if (q0 > last && q0 < mn) mn = q0;
                if (q1 > last && q1 < mn) mn = q1;
                if (q2 > last && q2 < mn) mn = q2;
                if (q3 > last && q3 < mn) mn = q3;
                mn = wave_min_u64(mn);
                if (l == 0) nbr[m * KNBR + S + r] = (int)(u32)mn;
                last = mn;
            }
        } else {
            for (int r = 0; r < need; r++) {
                u64 mn = ~0ull;
                for (int t = l; t < PCLOUD; t += 64) {
                    int j = base + t;
                    float px = pos[j * 3], py = pos[j * 3 + 1], pz = pos[j * 3 + 2];
                    float sp = __fadd_rn(__fadd_rn(__fmul_rn(px, px), __fmul_rn(py, py)), __fmul_rn(pz, pz));
                    float dt = __fadd_rn(__fadd_rn(__fmul_rn(cx, px), __fmul_rn(cy, py)), __fmul_rn(cz, pz));
                    float d2 = __fsub_rn(__fadd_rn(sc, sp), __fmul_rn(2.0f, dt));
                    if (d2 <= R2 && bktOf(d2) == B) {
                        u64 kk = d2key(d2, j);
                        if (kk > last && kk < mn) mn = kk;
                    }
                }
                mn = wave_min_u64(mn);
                if (l == 0) nbr[m * KNBR + S + r] = (int)(u32)mn;
                last = mn;
            }
        }
    }
}

// ======== MLP kernel: 2 waves/block, one center per wave (no launch_bounds) ========
__global__ void mlp_kernel(
    const float* __restrict__ x, const float* __restrict__ pos,
    const int* __restrict__ idx, const int* __restrict__ nbr,
    const int* __restrict__ nsel,
    const float* __restrict__ b1, const float* __restrict__ b2,
    const float* __restrict__ b3,
    const uint4* __restrict__ ws4, float* __restrict__ out) {
    __shared__ __align__(16) uint4 sA[2 * 512];   // 16 KB: per-wave 32x128 bf16 tile
    int tid = threadIdx.x, w = tid >> 6, l = tid & 63;
    int bid = blockIdx.x;
    int m = ((bid & 7) << 10) + ((bid >> 3) << 1) + w;   // grid 4096
    int nselm = nsel[m];
    int selj = (l < KNBR && l < nselm) ? nbr[m * KNBR + l] : -1;

    int ic = idx[m] & (8 * PCLOUD - 1);
    float cx = pos[ic * 3], cy = pos[ic * 3 + 1], cz = pos[ic * 3 + 2];

    // gather 32 feat rows into own sA tile (XOR 16B-chunk swizzle by row&7)
    uint4* sAw = sA + w * 512;
    u16*  sAw16 = (u16*)sAw;
    {
        int h = l & 1, rl = l >> 1;
        int j = __shfl(selj, rl);
        int xv = rl & 7;
        uint4* dst = sAw + rl * 16;
        uint4 z; z.x = z.y = z.z = z.w = 0;
        if (j >= 0) {
            const float4* sx = (const float4*)(x + (size_t)j * DIN);
            int c0lo = h ? 6 : 0, c0hi = h ? 8 : 6;
            for (int c0 = c0lo; c0 < c0hi; c0++) {
                float4 f0 = sx[c0 * 2], f1 = sx[c0 * 2 + 1];
                uint4 pv;
                pv.x = pk2(f0.x, f0.y); pv.y = pk2(f0.z, f0.w);
                pv.z = pk2(f1.x, f1.y); pv.w = pk2(f1.z, f1.w);
                dst[c0 ^ xv] = pv;
            }
            if (h == 1) {
                float rx = pos[j * 3] - cx, ry = pos[j * 3 + 1] - cy, rz = pos[j * 3 + 2] - cz;
                uint4 rc; rc.x = pk2(rx, ry); rc.y = (u32)f2bf(rz); rc.z = 0; rc.w = 0;
                dst[8 ^ xv] = rc;
                dst[9 ^ xv] = z; dst[10 ^ xv] = z; dst[11 ^ xv] = z;
            }
        } else {
            int c0lo = h ? 6 : 0, c0hi = h ? 12 : 6;
            for (int c0 = c0lo; c0 < c0hi; c0++) dst[c0 ^ xv] = z;
        }
    }
    LDS_FENCE();

    int m16 = l & 15, quad = l >> 4;
    const uint4* wsl = ws4 + l;
    const floatx4 vzero = {0.f, 0.f, 0.f, 0.f};

    // GEMM1: h1 = relu(feat @ W1 + b1), K=96
    {
        floatx4 acc[2][8];
        #pragma unroll
        for (int t = 0; t < 2; t++)
            #pragma unroll
            for (int cc = 0; cc < 8; cc++) acc[t][cc] = vzero;
        #pragma unroll
        for (int ki = 0; ki < 3; ki++) {
            bf16x8 a[2], b[8];
            int cb = ki * 4 + quad;
            #pragma unroll
            for (int t = 0; t < 2; t++) {
                int row = t * 16 + m16;
                a[t] = __builtin_bit_cast(bf16x8, sAw[row * 16 + (cb ^ (row & 7))]);
            }
            #pragma unroll
            for (int cc = 0; cc < 8; cc++)
                b[cc] = loadB<true>(wsl, cc * 3 + ki, 0, 0, 0, 0, 0);
            #pragma unroll
            for (int t = 0; t < 2; t++)
                #pragma unroll
                for (int cc = 0; cc < 8; cc++)
                    acc[t][cc] = __builtin_amdgcn_mfma_f32_16x16x32_bf16(a[t], b[cc], acc[t][cc], 0, 0, 0);
        }
        LDS_FENCE();
        #pragma unroll
        for (int t = 0; t < 2; t++)
            #pragma unroll
            for (int cc = 0; cc < 8; cc++) {
                int col = cc * 16 + m16;
                float bias = b1[col];
                #pragma unroll
                for (int i = 0; i < 4; i++) {
                    int rr = t * 16 + quad * 4 + i;
                    float v = fmaxf(acc[t][cc][i] + bias, 0.0f);
                    sAw16[rr * 128 + ((((col >> 3) ^ (rr & 7)) << 3) | (col & 7))] = f2bf(v);
                }
            }
    }
    LDS_FENCE();

    // GEMM2: h2 = relu(h1 @ W2 + b2), K=128
    {
        floatx4 acc[2][8];
        #pragma unroll
        for (int t = 0; t < 2; t++)
            #pragma unroll
            for (int cc = 0; cc < 8; cc++) acc[t][cc] = vzero;
        #pragma unroll
        for (int ki = 0; ki < 4; ki++) {
            bf16x8 a[2], b[8];
            int cb = ki * 4 + quad;
            #pragma unroll
            for (int t = 0; t < 2; t++) {
                int row = t * 16 + m16;
                a[t] = __builtin_bit_cast(bf16x8, sAw[row * 16 + (cb ^ (row & 7))]);
            }
            #pragma unroll
            for (int cc = 0; cc < 8; cc++)
                b[cc] = loadB<true>(wsl + 1536, cc * 4 + ki, 0, 0, 0, 0, 0);
            #pragma unroll
            for (int t = 0; t < 2; t++)
                #pragma unroll
                for (int cc = 0; cc < 8; cc++)
                    acc[t][cc] = __builtin_amdgcn_mfma_f32_16x16x32_bf16(a[t], b[cc], acc[t][cc], 0, 0, 0);
        }
        LDS_FENCE();
        #pragma unroll
        for (int t = 0; t < 2; t++)
            #pragma unroll
            for (int cc = 0; cc < 8; cc++) {
                int col = cc * 16 + m16;
                float bias = b2[col];
                #pragma unroll
                for (int i = 0; i < 4; i++) {
                    int rr = t * 16 + quad * 4 + i;
                    float v = fmaxf(acc[t][cc][i] + bias, 0.0f);
                    sAw16[rr * 128 + ((((col >> 3) ^ (rr & 7)) << 3) | (col & 7))] = f2bf(v);
                }
            }
    }
    LDS_FENCE();

    // GEMM3: h3 = relu(h2 @ W3 + b3), K=128, N=256 + wave-local masked max
    #pragma unroll
    for (int half = 0; half < 2; half++) {
        floatx4 acc[2][8];
        #pragma unroll
        for (int t = 0; t < 2; t++)
            #pragma unroll
            for (int cc = 0; cc < 8; cc++) acc[t][cc] = vzero;
        #pragma unroll
        for (int ki = 0; ki < 4; ki++) {
            bf16x8 a[2], b[8];
            int cb = ki * 4 + quad;
            #pragma unroll
            for (int t = 0; t < 2; t++) {
                int row = t * 16 + m16;
                a[t] = __builtin_bit_cast(bf16x8, sAw[row * 16 + (cb ^ (row & 7))]);
            }
            #pragma unroll
            for (int cc = 0; cc < 8; cc++)
                b[cc] = loadB<true>(wsl + 3584, (half * 8 + cc) * 4 + ki, 0, 0, 0, 0, 0);
            #pragma unroll
            for (int t = 0; t < 2; t++)
                #pragma unroll
                for (int cc = 0; cc < 8; cc++)
                    acc[t][cc] = __builtin_amdgcn_mfma_f32_16x16x32_bf16(a[t], b[cc], acc[t][cc], 0, 0, 0);
        }
        #pragma unroll
        for (int cc = 0; cc < 8; cc++) {
            int col = half * 128 + cc * 16 + m16;
            float bias = b3[col];
            float mv = 0.0f;
            #pragma unroll
            for (int t = 0; t < 2; t++)
                #pragma unroll
                for (int i = 0; i < 4; i++) {
                    int k = t * 16 + quad * 4 + i;
                    float v = fmaxf(acc[t][cc][i] + bias, 0.0f);
                    if (k < nselm) mv = fmaxf(mv, v);
                }
            mv = fmaxf(mv, __shfl_xor(mv, 16));
            mv = fmaxf(mv, __shfl_xor(mv, 32));
            if (quad == 0) out[m * 256 + col] = mv;
        }
    }
}

// ================= fallback: fused kernel (ws too small) =================
__global__ __launch_bounds__(256, 2) void sa_fused_kernel(
    const float* __restrict__ x, const float* __restrict__ pos,
    const int* __restrict__ batch, const int* __restrict__ idx,
    const float* __restrict__ W1, const float* __restrict__ b1,
    const float* __restrict__ W2, const float* __restrict__ b2,
    const float* __restrict__ W3, const float* __restrict__ b3,
    float* __restrict__ out) {
    __shared__ __align__(16) uint4 sA[4 * 512];
    __shared__ u32 hist[4][32];
    __shared__ int nbrl[4][32];
    __shared__ int cnts[4];

    int tid = threadIdx.x, w = tid >> 6, l = tid & 63;
    int bid = blockIdx.x;
    int m0 = ((bid & 7) << 10) + ((bid >> 3) << 2);
    int m = m0 + w;
    int ic = idx[m] & (8 * PCLOUD - 1);
    float cx = pos[ic * 3], cy = pos[ic * 3 + 1], cz = pos[ic * 3 + 2];
    float sc = __fadd_rn(__fadd_rn(__fmul_rn(cx, cx), __fmul_rn(cy, cy)), __fmul_rn(cz, cz));
    int bcl = batch[ic] & 7;
    int base = bcl << 12;
    const float R2 = 0.04f;

    if (l == 1) {
        float* o1 = out + MCENT * 256;
        o1[m * 3] = cx; o1[m * 3 + 1] = cy; o1[m * 3 + 2] = cz;
        (o1 + MCENT * 3)[m] = (float)bcl;
    }
    if (l < 32) hist[w][l] = 0;
    if (l == 0) cnts[w] = 0;
    LDS_FENCE();

    int c = 0;
    for (int t = l; t < PCLOUD; t += 64) {
        int j = base + t;
        float px = pos[j * 3], py = pos[j * 3 + 1], pz = pos[j * 3 + 2];
        float sp = __fadd_rn(__fadd_rn(__fmul_rn(px, px), __fmul_rn(py, py)), __fmul_rn(pz, pz));
        float dt = __fadd_rn(__fadd_rn(__fmul_rn(cx, px), __fmul_rn(cy, py)), __fmul_rn(cz, pz));
        float d2 = __fsub_rn(__fadd_rn(sc, sp), __fmul_rn(2.0f, dt));
        bool hit = (d2 <= R2);
        c += (int)__popcll(__ballot(hit));
        if (hit) atomicAdd(&hist[w][bktOf(d2)], 1u);
    }
    LDS_FENCE();
    int nsel = c < KNBR ? c : KNBR;

    int B = 32, S = 0;
    if (c > KNBR) {
        int hv = (l < 32) ? (int)hist[w][l] : 0;
        #pragma unroll
        for (int off = 1; off <= 16; off <<= 1) {
            int o = __shfl_up(hv, off);
            if (l >= off) hv += o;
        }
        u64 ge = __ballot((l < 32) && (hv >= KNBR));
        B = __ffsll((unsigned long long)ge) - 1;
        S = (B == 0) ? 0 : __shfl(hv, B - 1);
    }

    u64 q0 = ~0ull, q1 = ~0ull, q2 = ~0ull, q3 = ~0ull;
    int nq = 0;
    for (int t = l; t < PCLOUD; t += 64) {
        int j = base + t;
        float px = pos[j * 3], py = pos[j * 3 + 1], pz = pos[j * 3 + 2];
        float sp = __fadd_rn(__fadd_rn(__fmul_rn(px, px), __fmul_rn(py, py)), __fmul_rn(pz, pz));
        float dt = __fadd_rn(__fadd_rn(__fmul_rn(cx, px), __fmul_rn(cy, py)), __fmul_rn(cz, pz));
        float d2 = __fsub_rn(__fadd_rn(sc, sp), __fmul_rn(2.0f, dt));
        if (d2 <= R2) {
            int bkt = bktOf(d2);
            if (bkt < B) {
                int p = atomicAdd(&cnts[w], 1);
                nbrl[w][p] = j;
            } else if (bkt == B) {
                u64 kk = d2key(d2, j);
                if (nq == 0) q0 = kk; else if (nq == 1) q1 = kk;
                else if (nq == 2) q2 = kk; else if (nq == 3) q3 = kk;
                nq++;
            }
        }
    }
    if (c > KNBR) {
        int need = KNBR - S;
        u64 last = 0;
        if (__ballot(nq > 4) == 0ull) {
            for (int r = 0; r < need; r++) {
                u64 mn = ~0ull;
                if (q0 > last && q0 < mn) mn = q0;
                if (q1 > last && q1 < mn) mn = q1;
                if (q2 > last && q2 < mn) mn = q2;
                if (q3 > last && q3 < mn) mn = q3;
                mn = wave_min_u64(mn);
                if (l == 0) nbrl[w][S + r] = (int)(u32)mn;
                last = mn;
            }
        } else {
            for (int r = 0; r < need; r++) {
                u64 mn = ~0ull;
                for (int t = l; t < PCLOUD; t += 64) {
                    int j = base + t;
                    float px = pos[j * 3], py = pos[j * 3 + 1], pz = pos[j * 3 + 2];
                    float sp = __fadd_rn(__fadd_rn(__fmul_rn(px, px), __fmul_rn(py, py)), __fmul_rn(pz, pz));
                    float dt = __fadd_rn(__fadd_rn(__fmul_rn(cx, px), __fmul_rn(cy, py)), __fmul_rn(cz, pz));
                    float d2 = __fsub_rn(__fadd_rn(sc, sp), __fmul_rn(2.0f, dt));
                    if (d2 <= R2 && bktOf(d2) == B) {
                        u64 kk = d2key(d2, j);
                        if (kk > last && kk < mn) mn = kk;
                    }
                }
                mn = wave_min_u64(mn);
                if (l == 0) nbrl[w][S + r] = (int)(u32)mn;
                last = mn;
            }
        }
    }
    LDS_FENCE();
    int selj = (l < nsel) ? nbrl[w][l] : -1;

    uint4* sAw = sA + w * 512;
    u16*  sAw16 = (u16*)sAw;
    {
        int h = l & 1, rl = l >> 1;
        int j = __shfl(selj, rl);
        int xv = rl & 7;
        uint4* dst = sAw + rl * 16;
        uint4 z; z.x = z.y = z.z = z.w = 0;
        if (j >= 0) {
            const float4* sx = (const float4*)(x + (size_t)j * DIN);
            int c0lo = h ? 6 : 0, c0hi = h ? 8 : 6;
            for (int c0 = c0lo; c0 < c0hi; c0++) {
                float4 f0 = sx[c0 * 2], f1 = sx[c0 * 2 + 1];
                uint4 pv;
                pv.x = pk2(f0.x, f0.y); pv.y = pk2(f0.z, f0.w);
                pv.z = pk2(f1.x, f1.y); pv.w = pk2(f1.z, f1.w);
                dst[c0 ^ xv] = pv;
            }
            if (h == 1) {
                float rx = pos[j * 3] - cx, ry = pos[j * 3 + 1] - cy, rz = pos[j * 3 + 2] - cz;
                uint4 rc; rc.x = pk2(rx, ry); rc.y = (u32)f2bf(rz); rc.z = 0; rc.w = 0;
                dst[8 ^ xv] = rc;
                dst[9 ^ xv] = z; dst[10 ^ xv] = z; dst[11 ^ xv] = z;
            }
        } else {
            int c0lo = h ? 6 : 0, c0hi = h ? 12 : 6;
            for (int c0 = c0lo; c0 < c0hi; c0++) dst[c0 ^ xv] = z;
        }
    }
    LDS_FENCE();

    int m16 = l & 15, quad = l >> 4;
    const floatx4 vzero = {0.f, 0.f, 0.f, 0.f};

    {
        floatx4 acc[2][8];
        #pragma unroll
        for (int t = 0; t < 2; t++)
            #pragma unroll
            for (int cc = 0; cc < 8; cc++) acc[t][cc] = vzero;
        #pragma unroll
        for (int ki = 0; ki < 3; ki++) {
            bf16x8 a[2], b[8];
            int cb = ki * 4 + quad;
            #pragma unroll
            for (int t = 0; t < 2; t++) {
                int row = t * 16 + m16;
                a[t] = __builtin_bit_cast(bf16x8, sAw[row * 16 + (cb ^ (row & 7))]);
            }
            #pragma unroll
            for (int cc = 0; cc < 8; cc++)
                b[cc] = loadB<false>(0, 0, W1, 128, 67, cc * 16 + m16, cb * 8);
            #pragma unroll
            for (int t = 0; t < 2; t++)
                #pragma unroll
                for (int cc = 0; cc < 8; cc++)
                    acc[t][cc] = __builtin_amdgcn_mfma_f32_16x16x32_bf16(a[t], b[cc], acc[t][cc], 0, 0, 0);
        }
        LDS_FENCE();
        #pragma unroll
        for (int t = 0; t < 2; t++)
            #pragma unroll
            for (int cc = 0; cc < 8; cc++) {
                int col = cc * 16 + m16;
                float bias = b1[col];
                #pragma unroll
                for (int i = 0; i < 4; i++) {
                    int rr = t * 16 + quad * 4 + i;
                    float v = fmaxf(acc[t][cc][i] + bias, 0.0f);
                    sAw16[rr * 128 + ((((col >> 3) ^ (rr & 7)) << 3) | (col & 7))] = f2bf(v);
                }
            }
    }
    LDS_FENCE();
    {
        floatx4 acc[2][8];
        #pragma unroll
        for (int t = 0; t < 2; t++)
            #pragma unroll
            for (int cc = 0; cc < 8; cc++) acc[t][cc] = vzero;
        #pragma unroll
        for (int ki = 0; ki < 4; ki++) {
            bf16x8 a[2], b[8];
            int cb = ki * 4 + quad;
            #pragma unroll
            for (int t = 0; t < 2; t++) {
                int row = t * 16 + m16;
                a[t] = __builtin_bit_cast(bf16x8, sAw[row * 16 + (cb ^ (row & 7))]);
            }
            #pragma unroll
            for (int cc = 0; cc < 8; cc++)
                b[cc] = loadB<false>(0, 0, W2, 128, 128, cc * 16 + m16, cb * 8);
            #pragma unroll
            for (int t = 0; t < 2; t++)
                #pragma unroll
                for (int cc = 0; cc < 8; cc++)
                    acc[t][cc] = __builtin_amdgcn_mfma_f32_16x16x32_bf16(a[t], b[cc], acc[t][cc], 0, 0, 0);
        }
        LDS_FENCE();
        #pragma unroll
        for (int t = 0; t < 2; t++)
            #pragma unroll
            for (int cc = 0; cc < 8; cc++) {
                int col = cc * 16 + m16;
                float bias = b2[col];
                #pragma unroll
                for (int i = 0; i < 4; i++) {
                    int rr = t * 16 + quad * 4 + i;
                    float v = fmaxf(acc[t][cc][i] + bias, 0.0f);
                    sAw16[rr * 128 + ((((col >> 3) ^ (rr & 7)) << 3) | (col & 7))] = f2bf(v);
                }
            }
    }
    LDS_FENCE();
    #pragma unroll
    for (int half = 0; half < 2; half++) {
        floatx4 acc[2][8];
        #pragma unroll
        for (int t = 0; t < 2; t++)
            #pragma unroll
            for (int cc = 0; cc < 8; cc++) acc[t][cc] = vzero;
        #pragma unroll
        for (int ki = 0; ki < 4; ki++) {
            bf16x8 a[2], b[8];
            int cb = ki * 4 + quad;
            #pragma unroll
            for (int t = 0; t < 2; t++) {
                int row = t * 16 + m16;
                a[t] = __builtin_bit_cast(bf16x8, sAw[row * 16 + (cb ^ (row & 7))]);
            }
            #pragma unroll
            for (int cc = 0; cc < 8; cc++)
                b[cc] = loadB<false>(0, 0, W3, 256, 128, (half * 8 + cc) * 16 + m16, cb * 8);
            #pragma unroll
            for (int t = 0; t < 2; t++)
                #pragma unroll
                for (int cc = 0; cc < 8; cc++)
                    acc[t][cc] = __builtin_amdgcn_mfma_f32_16x16x32_bf16(a[t], b[cc], acc[t][cc], 0, 0, 0);
        }
        #pragma unroll
        for (int cc = 0; cc < 8; cc++) {
            int col = half * 128 + cc * 16 + m16;
            float bias = b3[col];
            float mv = 0.0f;
            #pragma unroll
            for (int t = 0; t < 2; t++)
                #pragma unroll
                for (int i = 0; i < 4; i++) {
                    int k = t * 16 + quad * 4 + i;
                    float v = fmaxf(acc[t][cc][i] + bias, 0.0f);
                    if (k < nsel) mv = fmaxf(mv, v);
                }
            mv = fmaxf(mv, __shfl_xor(mv, 16));
            mv = fmaxf(mv, __shfl_xor(mv, 32));
            if (quad == 0) out[m * 256 + col] = mv;
        }
    }
}

extern "C" void kernel_launch(void* const* d_in, const int* in_sizes, int n_in,
                              void* d_out, int out_size, void* d_ws, size_t ws_size,
                              hipStream_t stream) {
    const float* x     = (const float*)d_in[0];
    const float* pos   = (const float*)d_in[1];
    const int*   batch = (const int*)d_in[2];
    const int*   idx   = (const int*)d_in[3];
    const float* W1    = (const float*)d_in[4];
    const float* b1    = (const float*)d_in[5];
    const float* W2    = (const float*)d_in[6];
    const float* b2    = (const float*)d_in[7];
    const float* W3    = (const float*)d_in[8];
    const float* b3    = (const float*)d_in[9];
    float* out = (float*)d_out;

    if (ws_size >= (size_t)WS_NEED) {
        uint4* ws4 = (uint4*)d_ws;
        int* nbr  = (int*)((char*)d_ws + WS_NBR_B);
        int* nsel = (int*)((char*)d_ws + WS_NSEL_B);
        hipLaunchKernelGGL(prep_kernel, dim3(30), dim3(256), 0, stream, W1, W2, W3, ws4);
        hipLaunchKernelGGL(knn_kernel, dim3(MCENT / 4), dim3(256), 0, stream,
                           pos, batch, idx, nbr, nsel, out);
        hipLaunchKernelGGL(mlp_kernel, dim3(MCENT / 2), dim3(128), 0, stream,
                           x, pos, idx, nbr, nsel, b1, b2, b3, ws4, out);
    } else {
        hipLaunchKernelGGL(sa_fused_kernel, dim3(MCENT / 4), dim3(256), 0, stream,
                           x, pos, batch, idx, W1, b1, W2, b2, W3, b3, out);
    }
}

// Round 10
// 217.455 us; speedup vs baseline: 1.2715x; 1.2715x over previous
//
#include <hip/hip_runtime.h>

// SAModule (PointNet++ SA), R10.
// Reg-cap evidence: (256,2)->120 VGPR clean; (128,3)->84 spill; none->64 heavy
// spill. MFMA kernel needs explicit ~256 regs/wave => __launch_bounds__(128,2).
// KNN: R5-style LDS cloud staging + per-wave LDS candidate list; pass 2 and
// bucket-B selection run on the ~137-entry list, not a 4096-pt rescan.
//   prep_kernel : weights -> bf16 B-fragment image in ws
//   knn_kernel  : ball-query KNN -> nbr/nsel in ws   (LDS 62.6KB, 2 blocks/CU)
//   mlp_kernel  : gather -> MLP 67->128->128->256 (bf16 MFMA) -> masked max

typedef unsigned short u16;
typedef unsigned int u32;
typedef unsigned long long u64;
typedef __bf16 bf16x8 __attribute__((ext_vector_type(8)));
typedef float floatx4 __attribute__((ext_vector_type(4)));

#define PCLOUD 4096
#define DIN    64
#define MCENT  8192
#define KNBR   32
#define CAP    448

#define WS_W_U4   7680                    // weight image, uint4 count (120 KB)
#define WS_NBR_B  (WS_W_U4 * 16)          // byte offset of nbr[8192][32]
#define WS_NSEL_B (WS_NBR_B + MCENT * KNBR * 4)
#define WS_NEED   (WS_NSEL_B + MCENT * 4)

#define LDS_FENCE() asm volatile("s_waitcnt lgkmcnt(0)" ::: "memory")

__device__ inline u16 f2bf(float f) {          // RNE
    u32 b = __float_as_uint(f);
    b += 0x7fffu + ((b >> 16) & 1u);
    return (u16)(b >> 16);
}
__device__ inline u32 pk2(float a, float b) { return (u32)f2bf(a) | ((u32)f2bf(b) << 16); }
__device__ inline u64 wave_min_u64(u64 v) {
    #pragma unroll
    for (int off = 32; off; off >>= 1) {
        u64 o = __shfl_xor((unsigned long long)v, off);
        if (o < v) v = o;
    }
    return v;
}
__device__ inline u64 d2key(float d2, int j) {
    u32 u = __float_as_uint(d2);
    u = (u & 0x80000000u) ? ~u : (u | 0x80000000u);   // order-preserving map
    return ((u64)u << 32) | (u32)j;
}
__device__ inline int bktOf(float d2) {
    int b = (int)(d2 * 800.0f);                // 32 buckets over [0, 0.04]
    return b < 0 ? 0 : (b > 31 ? 31 : b);
}
__device__ inline int key_bucket(u64 k) {
    u32 hi = (u32)(k >> 32);
    if (hi < 0x80000000u) return 0;            // d2 <= -0
    float d2 = __uint_as_float(hi & 0x7fffffffu);
    return bktOf(d2);
}

// ---- prep: weights -> bf16 B-fragment image (layout: see loadB) ----
__global__ void prep_kernel(const float* __restrict__ W1, const float* __restrict__ W2,
                            const float* __restrict__ W3, uint4* __restrict__ ws) {
    int t = blockIdx.x * 256 + threadIdx.x;   // 0..7679
    const float* W; int rs, krows, KI, rel;
    if (t < 1536)      { W = W1; rs = 128; krows = 67;  KI = 3; rel = t; }
    else if (t < 3584) { W = W2; rs = 128; krows = 128; KI = 4; rel = t - 1536; }
    else               { W = W3; rs = 256; krows = 128; KI = 4; rel = t - 3584; }
    int m16 = rel & 15, quad = (rel >> 4) & 3, ccki = rel >> 6;
    int ki = ccki % KI, cc = ccki / KI;
    int n = cc * 16 + m16;
    int kb = (ki * 4 + quad) * 8;
    u16 e[8];
    #pragma unroll
    for (int j = 0; j < 8; j++)
        e[j] = (kb + j < krows) ? f2bf(W[(size_t)(kb + j) * rs + n]) : (u16)0;
    ws[t] = *(const uint4*)e;
}

template <bool WS>
__device__ __forceinline__ bf16x8 loadB(const uint4* __restrict__ wsl, int slot,
                                        const float* __restrict__ W, int rs, int krows,
                                        int n, int kb) {
    if constexpr (WS) {
        return __builtin_bit_cast(bf16x8, wsl[slot * 64]);
    } else {
        u16 e[8];
        #pragma unroll
        for (int j = 0; j < 8; j++)
            e[j] = (kb + j < krows) ? f2bf(W[(size_t)(kb + j) * rs + n]) : (u16)0;
        return __builtin_bit_cast(bf16x8, *(const uint4*)e);
    }
}

// ================= KNN kernel: 4 waves = 4 centers, shared cloud in LDS =================
__global__ __launch_bounds__(256, 2) void knn_kernel(
    const float* __restrict__ pos, const int* __restrict__ batch,
    const int* __restrict__ idx, int* __restrict__ nbr, int* __restrict__ nsel,
    float* __restrict__ out) {
    __shared__ float posLds[3 * PCLOUD];   // 48 KB
    __shared__ u64 lists[4][CAP];          // 14336 B
    __shared__ u32 hist[4][32];
    __shared__ int cnts[4], cnt2[4];

    int tid = threadIdx.x, w = tid >> 6, l = tid & 63;
    int bid = blockIdx.x;
    int m0 = ((bid & 7) << 10) + ((bid >> 3) << 2);   // XCD-friendly: bid%8 ~ cloud
    int m = m0 + w;
    int ic = idx[m] & (8 * PCLOUD - 1);
    float cx = pos[ic * 3], cy = pos[ic * 3 + 1], cz = pos[ic * 3 + 2];
    float sc = __fadd_rn(__fadd_rn(__fmul_rn(cx, cx), __fmul_rn(cy, cy)), __fmul_rn(cz, cz));
    int bcl = batch[ic] & 7;
    int base = bcl << 12;
    const float R2 = 0.04f;

    // cooperative cloud load (block-uniform cloud; mismatch handled below)
    int ic0 = idx[m0] & (8 * PCLOUD - 1);
    int bcl0 = batch[ic0] & 7;
    {
        const uint4* pg = (const uint4*)pos + (size_t)bcl0 * 3072;
        uint4* pl4 = (uint4*)posLds;
        #pragma unroll
        for (int i = 0; i < 12; i++) pl4[i * 256 + tid] = pg[i * 256 + tid];
    }
    if (l == 1) {
        float* o1 = out + MCENT * 256;
        o1[m * 3] = cx; o1[m * 3 + 1] = cy; o1[m * 3 + 2] = cz;
        (o1 + MCENT * 3)[m] = (float)bcl;
    }
    if (l < 32) hist[w][l] = 0;
    if (l == 0) { cnts[w] = 0; cnt2[w] = 0; }
    __syncthreads();

    // ---- pass 1: scan cloud (LDS), compact candidates + histogram (wave-private) ----
    bool useLds = (bcl == bcl0);
    if (useLds) {
        for (int t = l; t < PCLOUD; t += 64) {
            float px = posLds[t * 3], py = posLds[t * 3 + 1], pz = posLds[t * 3 + 2];
            float sp = __fadd_rn(__fadd_rn(__fmul_rn(px, px), __fmul_rn(py, py)), __fmul_rn(pz, pz));
            float dt = __fadd_rn(__fadd_rn(__fmul_rn(cx, px), __fmul_rn(cy, py)), __fmul_rn(cz, pz));
            float d2 = __fsub_rn(__fadd_rn(sc, sp), __fmul_rn(2.0f, dt));
            if (d2 <= R2) {
                int p = atomicAdd(&cnts[w], 1);
                atomicAdd(&hist[w][bktOf(d2)], 1u);
                if (p < CAP) lists[w][p] = d2key(d2, base + t);
            }
        }
    } else {
        for (int t = l; t < PCLOUD; t += 64) {
            int j = base + t;
            float px = pos[j * 3], py = pos[j * 3 + 1], pz = pos[j * 3 + 2];
            float sp = __fadd_rn(__fadd_rn(__fmul_rn(px, px), __fmul_rn(py, py)), __fmul_rn(pz, pz));
            float dt = __fadd_rn(__fadd_rn(__fmul_rn(cx, px), __fmul_rn(cy, py)), __fmul_rn(cz, pz));
            float d2 = __fsub_rn(__fadd_rn(sc, sp), __fmul_rn(2.0f, dt));
            if (d2 <= R2) {
                int p = atomicAdd(&cnts[w], 1);
                atomicAdd(&hist[w][bktOf(d2)], 1u);
                if (p < CAP) lists[w][p] = d2key(d2, j);
            }
        }
    }
    LDS_FENCE();
    int c = cnts[w];
    if (l == 0) nsel[m] = c < KNBR ? c : KNBR;

    if (c <= KNBR) {
        if (l < c) nbr[m * KNBR + l] = (int)(u32)lists[w][l];
    } else if (c <= CAP) {
        // threshold bucket B, below-count S
        int hv = (l < 32) ? (int)hist[w][l] : 0;
        #pragma unroll
        for (int off = 1; off <= 16; off <<= 1) {
            int o = __shfl_up(hv, off);
            if (l >= off) hv += o;
        }
        u64 ge = __ballot((l < 32) && (hv >= KNBR));
        int B = __ffsll((unsigned long long)ge) - 1;
        int S = (B == 0) ? 0 : __shfl(hv, B - 1);
        // pass 2 over the LDS list (~137 entries): bulk-select below B (order-free),
        // capture bucket-B keys in regs
        u64 q0 = ~0ull, q1 = ~0ull, q2 = ~0ull, q3 = ~0ull;
        int nq = 0;
        for (int s = l; s < c; s += 64) {
            u64 kk = lists[w][s];
            int bkt = key_bucket(kk);
            if (bkt < B) {
                int p = atomicAdd(&cnt2[w], 1);
                nbr[m * KNBR + p] = (int)(u32)kk;
            } else if (bkt == B) {
                if (nq == 0) q0 = kk; else if (nq == 1) q1 = kk;
                else if (nq == 2) q2 = kk; else if (nq == 3) q3 = kk;
                nq++;
            }
        }
        int need = KNBR - S;
        u64 last = 0;
        if (__ballot(nq > 4) == 0ull) {            // expected (bucket B ~4-8 keys)
            for (int r = 0; r < need; r++) {
                u64 mn = ~0ull;
                if (q0 > last && q0 < mn) mn = q0;
                if (q1 > last && q1 < mn) mn = q1;
                if (q2 > last && q2 < mn) mn = q2;
                if (q3 > last && q3 < mn) mn = q3;
                mn = wave_min_u64(mn);
                if (l == 0) nbr[m * KNBR + S + r] = (int)(u32)mn;
                last = mn;
            }
        } else {                                   // pathological: rounds over list
            for (int r = 0; r < need; r++) {
                u64 mn = ~0ull;
                for (int s = l; s < c; s += 64) {
                    u64 kk = lists[w][s];
                    if (key_bucket(kk) == B && kk > last && kk < mn) mn = kk;
                }
                mn = wave_min_u64(mn);
                if (l == 0) nbr[m * KNBR + S + r] = (int)(u32)mn;
                last = mn;
            }
        }
    } else {
        // overflow (never for uniform data): 32 streaming argmin rounds over cloud
        u64 last = 0;
        for (int r = 0; r < KNBR; r++) {
            u64 mn = ~0ull;
            for (int t = l; t < PCLOUD; t += 64) {
                int j = base + t;
                float px, py, pz;
                if (useLds) { px = posLds[t * 3]; py = posLds[t * 3 + 1]; pz = posLds[t * 3 + 2]; }
                else        { px = pos[j * 3];    py = pos[j * 3 + 1];    pz = pos[j * 3 + 2]; }
                float sp = __fadd_rn(__fadd_rn(__fmul_rn(px, px), __fmul_rn(py, py)), __fmul_rn(pz, pz));
                float dt = __fadd_rn(__fadd_rn(__fmul_rn(cx, px), __fmul_rn(cy, py)), __fmul_rn(cz, pz));
                float d2 = __fsub_rn(__fadd_rn(sc, sp), __fmul_rn(2.0f, dt));
                if (d2 <= R2) {
                    u64 kk = d2key(d2, j);
                    if (kk > last && kk < mn) mn = kk;
                }
            }
            mn = wave_min_u64(mn);
            if (l == 0) nbr[m * KNBR + r] = (int)(u32)mn;
            last = mn;
        }
    }
}

// ======== MLP kernel: 2 waves/block, one center per wave, (128,2) => 256-reg cap ========
__global__ __launch_bounds__(128, 2) void mlp_kernel(
    const float* __restrict__ x, const float* __restrict__ pos,
    const int* __restrict__ idx, const int* __restrict__ nbr,
    const int* __restrict__ nsel,
    const float* __restrict__ b1, const float* __restrict__ b2,
    const float* __restrict__ b3,
    const uint4* __restrict__ ws4, float* __restrict__ out) {
    __shared__ __align__(16) uint4 sA[2 * 512];   // 16 KB: per-wave 32x128 bf16 tile
    int tid = threadIdx.x, w = tid >> 6, l = tid & 63;
    int bid = blockIdx.x;
    int m = ((bid & 7) << 10) + ((bid >> 3) << 1) + w;   // grid 4096
    int nselm = nsel[m];
    int selj = (l < KNBR && l < nselm) ? nbr[m * KNBR + l] : -1;

    int ic = idx[m] & (8 * PCLOUD - 1);
    float cx = pos[ic * 3], cy = pos[ic * 3 + 1], cz = pos[ic * 3 + 2];

    // gather 32 feat rows into own sA tile (XOR 16B-chunk swizzle by row&7)
    uint4* sAw = sA + w * 512;
    u16*  sAw16 = (u16*)sAw;
    {
        int h = l & 1, rl = l >> 1;
        int j = __shfl(selj, rl);
        int xv = rl & 7;
        uint4* dst = sAw + rl * 16;
        uint4 z; z.x = z.y = z.z = z.w = 0;
        if (j >= 0) {
            const float4* sx = (const float4*)(x + (size_t)j * DIN);
            int c0lo = h ? 6 : 0, c0hi = h ? 8 : 6;
            for (int c0 = c0lo; c0 < c0hi; c0++) {
                float4 f0 = sx[c0 * 2], f1 = sx[c0 * 2 + 1];
                uint4 pv;
                pv.x = pk2(f0.x, f0.y); pv.y = pk2(f0.z, f0.w);
                pv.z = pk2(f1.x, f1.y); pv.w = pk2(f1.z, f1.w);
                dst[c0 ^ xv] = pv;
            }
            if (h == 1) {
                float rx = pos[j * 3] - cx, ry = pos[j * 3 + 1] - cy, rz = pos[j * 3 + 2] - cz;
                uint4 rc; rc.x = pk2(rx, ry); rc.y = (u32)f2bf(rz); rc.z = 0; rc.w = 0;
                dst[8 ^ xv] = rc;
                dst[9 ^ xv] = z; dst[10 ^ xv] = z; dst[11 ^ xv] = z;
            }
        } else {
            int c0lo = h ? 6 : 0, c0hi = h ? 12 : 6;
            for (int c0 = c0lo; c0 < c0hi; c0++) dst[c0 ^ xv] = z;
        }
    }
    LDS_FENCE();

    int m16 = l & 15, quad = l >> 4;
    const uint4* wsl = ws4 + l;
    const floatx4 vzero = {0.f, 0.f, 0.f, 0.f};

    // GEMM1: h1 = relu(feat @ W1 + b1), K=96
    {
        floatx4 acc[2][8];
        #pragma unroll
        for (int t = 0; t < 2; t++)
            #pragma unroll
            for (int cc = 0; cc < 8; cc++) acc[t][cc] = vzero;
        #pragma unroll
        for (int ki = 0; ki < 3; ki++) {
            bf16x8 a[2], b[8];
            int cb = ki * 4 + quad;
            #pragma unroll
            for (int t = 0; t < 2; t++) {
                int row = t * 16 + m16;
                a[t] = __builtin_bit_cast(bf16x8, sAw[row * 16 + (cb ^ (row & 7))]);
            }
            #pragma unroll
            for (int cc = 0; cc < 8; cc++)
                b[cc] = loadB<true>(wsl, cc * 3 + ki, 0, 0, 0, 0, 0);
            #pragma unroll
            for (int t = 0; t < 2; t++)
                #pragma unroll
                for (int cc = 0; cc < 8; cc++)
                    acc[t][cc] = __builtin_amdgcn_mfma_f32_16x16x32_bf16(a[t], b[cc], acc[t][cc], 0, 0, 0);
        }
        LDS_FENCE();
        #pragma unroll
        for (int t = 0; t < 2; t++)
            #pragma unroll
            for (int cc = 0; cc < 8; cc++) {
                int col = cc * 16 + m16;
                float bias = b1[col];
                #pragma unroll
                for (int i = 0; i < 4; i++) {
                    int rr = t * 16 + quad * 4 + i;
                    float v = fmaxf(acc[t][cc][i] + bias, 0.0f);
                    sAw16[rr * 128 + ((((col >> 3) ^ (rr & 7)) << 3) | (col & 7))] = f2bf(v);
                }
            }
    }
    LDS_FENCE();

    // GEMM2: h2 = relu(h1 @ W2 + b2), K=128
    {
        floatx4 acc[2][8];
        #pragma unroll
        for (int t = 0; t < 2; t++)
            #pragma unroll
            for (int cc = 0; cc < 8; cc++) acc[t][cc] = vzero;
        #pragma unroll
        for (int ki = 0; ki < 4; ki++) {
            bf16x8 a[2], b[8];
            int cb = ki * 4 + quad;
            #pragma unroll
            for (int t = 0; t < 2; t++) {
                int row = t * 16 + m16;
                a[t] = __builtin_bit_cast(bf16x8, sAw[row * 16 + (cb ^ (row & 7))]);
            }
            #pragma unroll
            for (int cc = 0; cc < 8; cc++)
                b[cc] = loadB<true>(wsl + 1536, cc * 4 + ki, 0, 0, 0, 0, 0);
            #pragma unroll
            for (int t = 0; t < 2; t++)
                #pragma unroll
                for (int cc = 0; cc < 8; cc++)
                    acc[t][cc] = __builtin_amdgcn_mfma_f32_16x16x32_bf16(a[t], b[cc], acc[t][cc], 0, 0, 0);
        }
        LDS_FENCE();
        #pragma unroll
        for (int t = 0; t < 2; t++)
            #pragma unroll
            for (int cc = 0; cc < 8; cc++) {
                int col = cc * 16 + m16;
                float bias = b2[col];
                #pragma unroll
                for (int i = 0; i < 4; i++) {
                    int rr = t * 16 + quad * 4 + i;
                    float v = fmaxf(acc[t][cc][i] + bias, 0.0f);
                    sAw16[rr * 128 + ((((col >> 3) ^ (rr & 7)) << 3) | (col & 7))] = f2bf(v);
                }
            }
    }
    LDS_FENCE();

    // GEMM3: h3 = relu(h2 @ W3 + b3), K=128, N=256 + wave-local masked max
    #pragma unroll
    for (int half = 0; half < 2; half++) {
        floatx4 acc[2][8];
        #pragma unroll
        for (int t = 0; t < 2; t++)
            #pragma unroll
            for (int cc = 0; cc < 8; cc++) acc[t][cc] = vzero;
        #pragma unroll
        for (int ki = 0; ki < 4; ki++) {
            bf16x8 a[2], b[8];
            int cb = ki * 4 + quad;
            #pragma unroll
            for (int t = 0; t < 2; t++) {
                int row = t * 16 + m16;
                a[t] = __builtin_bit_cast(bf16x8, sAw[row * 16 + (cb ^ (row & 7))]);
            }
            #pragma unroll
            for (int cc = 0; cc < 8; cc++)
                b[cc] = loadB<true>(wsl + 3584, (half * 8 + cc) * 4 + ki, 0, 0, 0, 0, 0);
            #pragma unroll
            for (int t = 0; t < 2; t++)
                #pragma unroll
                for (int cc = 0; cc < 8; cc++)
                    acc[t][cc] = __builtin_amdgcn_mfma_f32_16x16x32_bf16(a[t], b[cc], acc[t][cc], 0, 0, 0);
        }
        #pragma unroll
        for (int cc = 0; cc < 8; cc++) {
            int col = half * 128 + cc * 16 + m16;
            float bias = b3[col];
            float mv = 0.0f;   // post-ReLU max over >=1 valid nbr is >= 0
            #pragma unroll
            for (int t = 0; t < 2; t++)
                #pragma unroll
                for (int i = 0; i < 4; i++) {
                    int k = t * 16 + quad * 4 + i;
                    float v = fmaxf(acc[t][cc][i] + bias, 0.0f);
                    if (k < nselm) mv = fmaxf(mv, v);
                }
            mv = fmaxf(mv, __shfl_xor(mv, 16));
            mv = fmaxf(mv, __shfl_xor(mv, 32));
            if (quad == 0) out[m * 256 + col] = mv;
        }
    }
}

// ================= fallback: fused kernel (ws too small) =================
__global__ __launch_bounds__(256, 2) void sa_fused_kernel(
    const float* __restrict__ x, const float* __restrict__ pos,
    const int* __restrict__ batch, const int* __restrict__ idx,
    const float* __restrict__ W1, const float* __restrict__ b1,
    const float* __restrict__ W2, const float* __restrict__ b2,
    const float* __restrict__ W3, const float* __restrict__ b3,
    float* __restrict__ out) {
    __shared__ __align__(16) uint4 sA[4 * 512];
    __shared__ u32 hist[4][32];
    __shared__ int nbrl[4][32];
    __shared__ int cnts[4];

    int tid = threadIdx.x, w = tid >> 6, l = tid & 63;
    int bid = blockIdx.x;
    int m0 = ((bid & 7) << 10) + ((bid >> 3) << 2);
    int m = m0 + w;
    int ic = idx[m] & (8 * PCLOUD - 1);
    float cx = pos[ic * 3], cy = pos[ic * 3 + 1], cz = pos[ic * 3 + 2];
    float sc = __fadd_rn(__fadd_rn(__fmul_rn(cx, cx), __fmul_rn(cy, cy)), __fmul_rn(cz, cz));
    int bcl = batch[ic] & 7;
    int base = bcl << 12;
    const float R2 = 0.04f;

    if (l == 1) {
        float* o1 = out + MCENT * 256;
        o1[m * 3] = cx; o1[m * 3 + 1] = cy; o1[m * 3 + 2] = cz;
        (o1 + MCENT * 3)[m] = (float)bcl;
    }
    if (l < 32) hist[w][l] = 0;
    if (l == 0) cnts[w] = 0;
    LDS_FENCE();

    int c = 0;
    for (int t = l; t < PCLOUD; t += 64) {
        int j = base + t;
        float px = pos[j * 3], py = pos[j * 3 + 1], pz = pos[j * 3 + 2];
        float sp = __fadd_rn(__fadd_rn(__fmul_rn(px, px), __fmul_rn(py, py)), __fmul_rn(pz, pz));
        float dt = __fadd_rn(__fadd_rn(__fmul_rn(cx, px), __fmul_rn(cy, py)), __fmul_rn(cz, pz));
        float d2 = __fsub_rn(__fadd_rn(sc, sp), __fmul_rn(2.0f, dt));
        bool hit = (d2 <= R2);
        c += (int)__popcll(__ballot(hit));
        if (hit) atomicAdd(&hist[w][bktOf(d2)], 1u);
    }
    LDS_FENCE();
    int nsel = c < KNBR ? c : KNBR;

    int B = 32, S = 0;
    if (c > KNBR) {
        int hv = (l < 32) ? (int)hist[w][l] : 0;
        #pragma unroll
        for (int off = 1; off <= 16; off <<= 1) {
            int o = __shfl_up(hv, off);
            if (l >= off) hv += o;
        }
        u64 ge = __ballot((l < 32) && (hv >= KNBR));
        B = __ffsll((unsigned long long)ge) - 1;
        S = (B == 0) ? 0 : __shfl(hv, B - 1);
    }

    u64 q0 = ~0ull, q1 = ~0ull, q2 = ~0ull, q3 = ~0ull;
    int nq = 0;
    for (int t = l; t < PCLOUD; t += 64) {
        int j = base + t;
        float px = pos[j * 3], py = pos[j * 3 + 1], pz = pos[j * 3 + 2];
        float sp = __fadd_rn(__fadd_rn(__fmul_rn(px, px), __fmul_rn(py, py)), __fmul_rn(pz, pz));
        float dt = __fadd_rn(__fadd_rn(__fmul_rn(cx, px), __fmul_rn(cy, py)), __fmul_rn(cz, pz));
        float d2 = __fsub_rn(__fadd_rn(sc, sp), __fmul_rn(2.0f, dt));
        if (d2 <= R2) {
            int bkt = bktOf(d2);
            if (bkt < B) {
                int p = atomicAdd(&cnts[w], 1);
                nbrl[w][p] = j;
            } else if (bkt == B) {
                u64 kk = d2key(d2, j);
                if (nq == 0) q0 = kk; else if (nq == 1) q1 = kk;
                else if (nq == 2) q2 = kk; else if (nq == 3) q3 = kk;
                nq++;
            }
        }
    }
    if (c > KNBR) {
        int need = KNBR - S;
        u64 last = 0;
        if (__ballot(nq > 4) == 0ull) {
            for (int r = 0; r < need; r++) {
                u64 mn = ~0ull;
                if (q0 > last && q0 < mn) mn = q0;
                if (q1 > last && q1 < mn) mn = q1;
                if (q2 > last && q2 < mn) mn = q2;
                if (q3 > last && q3 < mn) mn = q3;
                mn = wave_min_u64(mn);
                if (l == 0) nbrl[w][S + r] = (int)(u32)mn;
                last = mn;
            }
        } else {
            for (int r = 0; r < need; r++) {
                u64 mn = ~0ull;
                for (int t = l; t < PCLOUD; t += 64) {
                    int j = base + t;
                    float px = pos[j * 3], py = pos[j * 3 + 1], pz = pos[j * 3 + 2];
                    float sp = __fadd_rn(__fadd_rn(__fmul_rn(px, px), __fmul_rn(py, py)), __fmul_rn(pz, pz));
                    float dt = __fadd_rn(__fadd_rn(__fmul_rn(cx, px), __fmul_rn(cy, py)), __fmul_rn(cz, pz));
                    float d2 = __fsub_rn(__fadd_rn(sc, sp), __fmul_rn(2.0f, dt));
                    if (d2 <= R2 && bktOf(d2) == B) {
                        u64 kk = d2key(d2, j);
                        if (kk > last && kk < mn) mn = kk;
                    }
                }
                mn = wave_min_u64(mn);
                if (l == 0) nbrl[w][S + r] = (int)(u32)mn;
                last = mn;
            }
        }
    }
    LDS_FENCE();
    int selj = (l < nsel) ? nbrl[w][l] : -1;

    uint4* sAw = sA + w * 512;
    u16*  sAw16 = (u16*)sAw;
    {
        int h = l & 1, rl = l >> 1;
        int j = __shfl(selj, rl);
        int xv = rl & 7;
        uint4* dst = sAw + rl * 16;
        uint4 z; z.x = z.y = z.z = z.w = 0;
        if (j >= 0) {
            const float4* sx = (const float4*)(x + (size_t)j * DIN);
            int c0lo = h ? 6 : 0, c0hi = h ? 8 : 6;
            for (int c0 = c0lo; c0 < c0hi; c0++) {
                float4 f0 = sx[c0 * 2], f1 = sx[c0 * 2 + 1];
                uint4 pv;
                pv.x = pk2(f0.x, f0.y); pv.y = pk2(f0.z, f0.w);
                pv.z = pk2(f1.x, f1.y); pv.w = pk2(f1.z, f1.w);
                dst[c0 ^ xv] = pv;
            }
            if (h == 1) {
                float rx = pos[j * 3] - cx, ry = pos[j * 3 + 1] - cy, rz = pos[j * 3 + 2] - cz;
                uint4 rc; rc.x = pk2(rx, ry); rc.y = (u32)f2bf(rz); rc.z = 0; rc.w = 0;
                dst[8 ^ xv] = rc;
                dst[9 ^ xv] = z; dst[10 ^ xv] = z; dst[11 ^ xv] = z;
            }
        } else {
            int c0lo = h ? 6 : 0, c0hi = h ? 12 : 6;
            for (int c0 = c0lo; c0 < c0hi; c0++) dst[c0 ^ xv] = z;
        }
    }
    LDS_FENCE();

    int m16 = l & 15, quad = l >> 4;
    const floatx4 vzero = {0.f, 0.f, 0.f, 0.f};

    {
        floatx4 acc[2][8];
        #pragma unroll
        for (int t = 0; t < 2; t++)
            #pragma unroll
            for (int cc = 0; cc < 8; cc++) acc[t][cc] = vzero;
        #pragma unroll
        for (int ki = 0; ki < 3; ki++) {
            bf16x8 a[2], b[8];
            int cb = ki * 4 + quad;
            #pragma unroll
            for (int t = 0; t < 2; t++) {
                int row = t * 16 + m16;
                a[t] = __builtin_bit_cast(bf16x8, sAw[row * 16 + (cb ^ (row & 7))]);
            }
            #pragma unroll
            for (int cc = 0; cc < 8; cc++)
                b[cc] = loadB<false>(0, 0, W1, 128, 67, cc * 16 + m16, cb * 8);
            #pragma unroll
            for (int t = 0; t < 2; t++)
                #pragma unroll
                for (int cc = 0; cc < 8; cc++)
                    acc[t][cc] = __builtin_amdgcn_mfma_f32_16x16x32_bf16(a[t], b[cc], acc[t][cc], 0, 0, 0);
        }
        LDS_FENCE();
        #pragma unroll
        for (int t = 0; t < 2; t++)
            #pragma unroll
            for (int cc = 0; cc < 8; cc++) {
                int col = cc * 16 + m16;
                float bias = b1[col];
                #pragma unroll
                for (int i = 0; i < 4; i++) {
                    int rr = t * 16 + quad * 4 + i;
                    float v = fmaxf(acc[t][cc][i] + bias, 0.0f);
                    sAw16[rr * 128 + ((((col >> 3) ^ (rr & 7)) << 3) | (col & 7))] = f2bf(v);
                }
            }
    }
    LDS_FENCE();
    {
        floatx4 acc[2][8];
        #pragma unroll
        for (int t = 0; t < 2; t++)
            #pragma unroll
            for (int cc = 0; cc < 8; cc++) acc[t][cc] = vzero;
        #pragma unroll
        for (int ki = 0; ki < 4; ki++) {
            bf16x8 a[2], b[8];
            int cb = ki * 4 + quad;
            #pragma unroll
            for (int t = 0; t < 2; t++) {
                int row = t * 16 + m16;
                a[t] = __builtin_bit_cast(bf16x8, sAw[row * 16 + (cb ^ (row & 7))]);
            }
            #pragma unroll
            for (int cc = 0; cc < 8; cc++)
                b[cc] = loadB<false>(0, 0, W2, 128, 128, cc * 16 + m16, cb * 8);
            #pragma unroll
            for (int t = 0; t < 2; t++)
                #pragma unroll
                for (int cc = 0; cc < 8; cc++)
                    acc[t][cc] = __builtin_amdgcn_mfma_f32_16x16x32_bf16(a[t], b[cc], acc[t][cc], 0, 0, 0);
        }
        LDS_FENCE();
        #pragma unroll
        for (int t = 0; t < 2; t++)
            #pragma unroll
            for (int cc = 0; cc < 8; cc++) {
                int col = cc * 16 + m16;
                float bias = b2[col];
                #pragma unroll
                for (int i = 0; i < 4; i++) {
                    int rr = t * 16 + quad * 4 + i;
                    float v = fmaxf(acc[t][cc][i] + bias, 0.0f);
                    sAw16[rr * 128 + ((((col >> 3) ^ (rr & 7)) << 3) | (col & 7))] = f2bf(v);
                }
            }
    }
    LDS_FENCE();
    #pragma unroll
    for (int half = 0; half < 2; half++) {
        floatx4 acc[2][8];
        #pragma unroll
        for (int t = 0; t < 2; t++)
            #pragma unroll
            for (int cc = 0; cc < 8; cc++) acc[t][cc] = vzero;
        #pragma unroll
        for (int ki = 0; ki < 4; ki++) {
            bf16x8 a[2], b[8];
            int cb = ki * 4 + quad;
            #pragma unroll
            for (int t = 0; t < 2; t++) {
                int row = t * 16 + m16;
                a[t] = __builtin_bit_cast(bf16x8, sAw[row * 16 + (cb ^ (row & 7))]);
            }
            #pragma unroll
            for (int cc = 0; cc < 8; cc++)
                b[cc] = loadB<false>(0, 0, W3, 256, 128, (half * 8 + cc) * 16 + m16, cb * 8);
            #pragma unroll
            for (int t = 0; t < 2; t++)
                #pragma unroll
                for (int cc = 0; cc < 8; cc++)
                    acc[t][cc] = __builtin_amdgcn_mfma_f32_16x16x32_bf16(a[t], b[cc], acc[t][cc], 0, 0, 0);
        }
        #pragma unroll
        for (int cc = 0; cc < 8; cc++) {
            int col = half * 128 + cc * 16 + m16;
            float bias = b3[col];
            float mv = 0.0f;
            #pragma unroll
            for (int t = 0; t < 2; t++)
                #pragma unroll
                for (int i = 0; i < 4; i++) {
                    int k = t * 16 + quad * 4 + i;
                    float v = fmaxf(acc[t][cc][i] + bias, 0.0f);
                    if (k < nsel) mv = fmaxf(mv, v);
                }
            mv = fmaxf(mv, __shfl_xor(mv, 16));
            mv = fmaxf(mv, __shfl_xor(mv, 32));
            if (quad == 0) out[m * 256 + col] = mv;
        }
    }
}

extern "C" void kernel_launch(void* const* d_in, const int* in_sizes, int n_in,
                              void* d_out, int out_size, void* d_ws, size_t ws_size,
                              hipStream_t stream) {
    const float* x     = (const float*)d_in[0];
    const float* pos   = (const float*)d_in[1];
    const int*   batch = (const int*)d_in[2];
    const int*   idx   = (const int*)d_in[3];
    const float* W1    = (const float*)d_in[4];
    const float* b1    = (const float*)d_in[5];
    const float* W2    = (const float*)d_in[6];
    const float* b2    = (const float*)d_in[7];
    const float* W3    = (const float*)d_in[8];
    const float* b3    = (const float*)d_in[9];
    float* out = (float*)d_out;

    if (ws_size >= (size_t)WS_NEED) {
        uint4* ws4 = (uint4*)d_ws;
        int* nbr  = (int*)((char*)d_ws + WS_NBR_B);
        int* nsel = (int*)((char*)d_ws + WS_NSEL_B);
        hipLaunchKernelGGL(prep_kernel, dim3(30), dim3(256), 0, stream, W1, W2, W3, ws4);
        hipLaunchKernelGGL(knn_kernel, dim3(MCENT / 4), dim3(256), 0, stream,
                           pos, batch, idx, nbr, nsel, out);
        hipLaunchKernelGGL(mlp_kernel, dim3(MCENT / 2), dim3(128), 0, stream,
                           x, pos, idx, nbr, nsel, b1, b2, b3, ws4, out);
    } else {
        hipLaunchKernelGGL(sa_fused_kernel, dim3(MCENT / 4), dim3(256), 0, stream,
                           x, pos, batch, idx, W1, b1, W2, b2, W3, b3, out);
    }
}